// Round 1
// baseline (1226.722 us; speedup 1.0000x reference)
//
#include <hip/hip_runtime.h>

#define NN 100000
#define EE 640000
#define DD 128

typedef short bf16x8 __attribute__((ext_vector_type(8)));
typedef float f32x4 __attribute__((ext_vector_type(4)));

__device__ __forceinline__ unsigned short f2bf(float f) {
    union { float f; unsigned int u; } a; a.f = f;
    unsigned int u = a.u + 0x7fffu + ((a.u >> 16) & 1u);   // RNE
    return (unsigned short)(u >> 16);
}

// ---------------- scatter: h0[col[e]] += x[row[e]] (h0 pre-initialized to x) ----
__global__ __launch_bounds__(256) void k_scatter(const int* __restrict__ ei,
                                                 const float* __restrict__ x,
                                                 float* __restrict__ h0) {
    int t = blockIdx.x * 256 + threadIdx.x;
    int e = t >> 5;                  // 32 lanes per edge: 32 * float4 = 512B row
    if (e >= EE) return;
    int lane = t & 31;
    int r = ei[e];                   // edge_index[0][e]
    int c = ei[EE + e];              // edge_index[1][e]
    float4 v = *reinterpret_cast<const float4*>(x + (size_t)r * DD + lane * 4);
    float* dst = h0 + (size_t)c * DD + lane * 4;
    unsafeAtomicAdd(dst + 0, v.x);
    unsafeAtomicAdd(dst + 1, v.y);
    unsafeAtomicAdd(dst + 2, v.z);
    unsafeAtomicAdd(dst + 3, v.w);
}

// ---------------- prep: Wt[n][k] = bf16(W[k][n]) for both layers ----------------
__global__ __launch_bounds__(256) void k_prep(const float* __restrict__ W1,
                                              const float* __restrict__ W2,
                                              unsigned short* __restrict__ w1t,
                                              unsigned short* __restrict__ w2t) {
    int idx = blockIdx.x * 256 + threadIdx.x;
    if (idx >= 2 * DD * DD) return;
    const float* W = (idx < DD * DD) ? W1 : W2;
    unsigned short* O = (idx < DD * DD) ? w1t : w2t;
    int i = idx & (DD * DD - 1);
    int n = i >> 7, k = i & (DD - 1);
    O[i] = f2bf(W[k * DD + n]);      // O[n*128 + k] = W[k][n]
}

// ---------------- fused MLP: out = relu(h0@W1+b1)@W2 + b2 ----------------------
// block = 256 thr = 4 waves in 2x2; block tile 128 rows x 128 cols; K=128.
// LDS: one 128x128 bf16 buffer (32KB), XOR-swizzled (byte ^= (row&7)<<4),
// reused for h0 then h1.
__global__ __launch_bounds__(256, 2) void k_mlp(const float* __restrict__ h0,
                                                const unsigned short* __restrict__ w1t,
                                                const unsigned short* __restrict__ w2t,
                                                const float* __restrict__ b1,
                                                const float* __restrict__ b2,
                                                float* __restrict__ out) {
    __shared__ unsigned short lds[DD * DD];  // 32 KB
    const int t  = threadIdx.x;
    const int w  = t >> 6, l = t & 63;
    const int wr = w >> 1, wc = w & 1;       // wave owns rows wr*64.., cols wc*64..
    const int hi = l >> 4, lo = l & 15;
    const long base_row = (long)blockIdx.x * 128;

    // B1 fragments: lane needs W1[k0+hi*8+i][col]; Wt layout makes this 16B contiguous.
    bf16x8 bw1[4][4];
#pragma unroll
    for (int n = 0; n < 4; ++n)
#pragma unroll
        for (int k = 0; k < 4; ++k)
            bw1[n][k] = *reinterpret_cast<const bf16x8*>(
                w1t + (wc * 64 + n * 16 + lo) * DD + k * 32 + hi * 8);

    // stage h0 -> LDS bf16 (swizzled)
#pragma unroll
    for (int it = 0; it < 16; ++it) {
        int idx = it * 1024 + t * 4;
        int row = idx >> 7, col = idx & (DD - 1);
        long g = base_row + row;
        float4 v = make_float4(0.f, 0.f, 0.f, 0.f);
        if (g < NN) v = *reinterpret_cast<const float4*>(h0 + g * DD + col);
        unsigned int u0 = (unsigned)f2bf(v.x) | ((unsigned)f2bf(v.y) << 16);
        unsigned int u1 = (unsigned)f2bf(v.z) | ((unsigned)f2bf(v.w) << 16);
        int byte = (row * 256 + col * 2) ^ ((row & 7) << 4);
        *reinterpret_cast<uint2*>(reinterpret_cast<char*>(lds) + byte) = make_uint2(u0, u1);
    }
    __syncthreads();

    const f32x4 zero = {0.f, 0.f, 0.f, 0.f};

    // GEMM1
    f32x4 acc[4][4];
#pragma unroll
    for (int m = 0; m < 4; ++m)
#pragma unroll
        for (int n = 0; n < 4; ++n) acc[m][n] = zero;
#pragma unroll
    for (int m = 0; m < 4; ++m) {
        bf16x8 a[4];
        int r = wr * 64 + m * 16 + lo;
#pragma unroll
        for (int k = 0; k < 4; ++k) {
            int byte = (r * 256 + k * 64 + hi * 16) ^ ((r & 7) << 4);
            a[k] = *reinterpret_cast<const bf16x8*>(reinterpret_cast<const char*>(lds) + byte);
        }
#pragma unroll
        for (int n = 0; n < 4; ++n)
#pragma unroll
            for (int k = 0; k < 4; ++k)
                acc[m][n] = __builtin_amdgcn_mfma_f32_16x16x32_bf16(a[k], bw1[n][k], acc[m][n], 0, 0, 0);
    }
    __syncthreads();   // all h0 reads done before overwrite

    // epilogue 1: h1 = relu(acc + b1) -> LDS bf16 (same buffer, swizzled)
    float bias1[4];
#pragma unroll
    for (int n = 0; n < 4; ++n) bias1[n] = b1[wc * 64 + n * 16 + lo];
#pragma unroll
    for (int m = 0; m < 4; ++m)
#pragma unroll
        for (int n = 0; n < 4; ++n)
#pragma unroll
            for (int g = 0; g < 4; ++g) {
                int row = wr * 64 + m * 16 + hi * 4 + g;   // D: col=lane&15, row=(lane>>4)*4+reg
                int col = wc * 64 + n * 16 + lo;
                float v = fmaxf(acc[m][n][g] + bias1[n], 0.f);
                int byte = (row * 256 + col * 2) ^ ((row & 7) << 4);
                *reinterpret_cast<unsigned short*>(reinterpret_cast<char*>(lds) + byte) = f2bf(v);
            }
    __syncthreads();

    // B2 fragments + GEMM2
    bf16x8 bw2[4][4];
#pragma unroll
    for (int n = 0; n < 4; ++n)
#pragma unroll
        for (int k = 0; k < 4; ++k)
            bw2[n][k] = *reinterpret_cast<const bf16x8*>(
                w2t + (wc * 64 + n * 16 + lo) * DD + k * 32 + hi * 8);

    f32x4 acc2[4][4];
#pragma unroll
    for (int m = 0; m < 4; ++m)
#pragma unroll
        for (int n = 0; n < 4; ++n) acc2[m][n] = zero;
#pragma unroll
    for (int m = 0; m < 4; ++m) {
        bf16x8 a[4];
        int r = wr * 64 + m * 16 + lo;
#pragma unroll
        for (int k = 0; k < 4; ++k) {
            int byte = (r * 256 + k * 64 + hi * 16) ^ ((r & 7) << 4);
            a[k] = *reinterpret_cast<const bf16x8*>(reinterpret_cast<const char*>(lds) + byte);
        }
#pragma unroll
        for (int n = 0; n < 4; ++n)
#pragma unroll
            for (int k = 0; k < 4; ++k)
                acc2[m][n] = __builtin_amdgcn_mfma_f32_16x16x32_bf16(a[k], bw2[n][k], acc2[m][n], 0, 0, 0);
    }

    // store out = acc2 + b2 (f32)
    float bias2[4];
#pragma unroll
    for (int n = 0; n < 4; ++n) bias2[n] = b2[wc * 64 + n * 16 + lo];
#pragma unroll
    for (int m = 0; m < 4; ++m)
#pragma unroll
        for (int n = 0; n < 4; ++n)
#pragma unroll
            for (int g = 0; g < 4; ++g) {
                long row = base_row + wr * 64 + m * 16 + hi * 4 + g;
                if (row < NN)
                    out[row * DD + wc * 64 + n * 16 + lo] = acc2[m][n][g] + bias2[n];
            }
}

extern "C" void kernel_launch(void* const* d_in, const int* in_sizes, int n_in,
                              void* d_out, int out_size, void* d_ws, size_t ws_size,
                              hipStream_t stream) {
    const float* x  = (const float*)d_in[0];
    const int*   ei = (const int*)d_in[1];
    const float* W1 = (const float*)d_in[2];
    const float* b1 = (const float*)d_in[3];
    const float* W2 = (const float*)d_in[4];
    const float* b2 = (const float*)d_in[5];
    float* out = (float*)d_out;

    float* h0 = (float*)d_ws;
    const size_t h0_bytes = (size_t)NN * DD * sizeof(float);   // 51.2 MB
    unsigned short* w1t = (unsigned short*)((char*)d_ws + h0_bytes);
    unsigned short* w2t = w1t + DD * DD;

    // h0 = x  (EPS=0: h = x + aggregated)
    hipMemcpyAsync(h0, x, h0_bytes, hipMemcpyDeviceToDevice, stream);
    k_prep<<<(2 * DD * DD + 255) / 256, 256, 0, stream>>>(W1, W2, w1t, w2t);
    k_scatter<<<(EE * 32) / 256, 256, 0, stream>>>(ei, x, h0);
    k_mlp<<<(NN + 127) / 128, 256, 0, stream>>>(h0, w1t, w2t, b1, b2, out);
}

// Round 3
// 268.765 us; speedup vs baseline: 4.5643x; 4.5643x over previous
//
#include <hip/hip_runtime.h>

#define NN 100000
#define EE 640000
#define DD 128
#define NB 391   // ceil(NN/256)

typedef short bf16x8 __attribute__((ext_vector_type(8)));
typedef float f32x4 __attribute__((ext_vector_type(4)));

__device__ __forceinline__ unsigned short f2bf(float f) {
    union { float f; unsigned int u; } a; a.f = f;
    unsigned int u = a.u + 0x7fffu + ((a.u >> 16) & 1u);   // RNE
    return (unsigned short)(u >> 16);
}

__device__ __forceinline__ int wave_incl_scan(int v, int lane) {
#pragma unroll
    for (int d = 1; d < 64; d <<= 1) {
        int u = __shfl_up(v, d, 64);
        if (lane >= d) v += u;
    }
    return v;
}

// ---------------- CSR build ----------------------------------------------------
__global__ __launch_bounds__(256) void k_hist(const int* __restrict__ ei,
                                              int* __restrict__ deg) {
    int e = blockIdx.x * 256 + threadIdx.x;
    if (e >= EE) return;
    atomicAdd(&deg[ei[EE + e]], 1);
}

__global__ __launch_bounds__(256) void k_scan1(const int* __restrict__ deg,
                                               int* __restrict__ bsum) {
    int i = blockIdx.x * 256 + threadIdx.x;
    int v = (i < NN) ? deg[i] : 0;
#pragma unroll
    for (int d = 32; d; d >>= 1) v += __shfl_down(v, d, 64);
    __shared__ int wsum[4];
    if ((threadIdx.x & 63) == 0) wsum[threadIdx.x >> 6] = v;
    __syncthreads();
    if (threadIdx.x == 0) bsum[blockIdx.x] = wsum[0] + wsum[1] + wsum[2] + wsum[3];
}

__global__ __launch_bounds__(512) void k_scan2(int* __restrict__ bsum,
                                               int* __restrict__ offs) {
    int t = threadIdx.x, lane = t & 63, w = t >> 6;
    int v = (t < NB) ? bsum[t] : 0;
    int s = wave_incl_scan(v, lane);
    __shared__ int wsum[8];
    if (lane == 63) wsum[w] = s;
    __syncthreads();
    int off = 0;
    for (int k = 0; k < w; ++k) off += wsum[k];
    if (t < NB) bsum[t] = off + s - v;   // exclusive block offsets
    if (t == 0) offs[NN] = EE;
}

__global__ __launch_bounds__(256) void k_scan3(const int* __restrict__ deg,
                                               const int* __restrict__ bsum,
                                               int* __restrict__ offs) {
    int t = threadIdx.x, lane = t & 63, w = t >> 6;
    int i = blockIdx.x * 256 + t;
    int v = (i < NN) ? deg[i] : 0;
    int s = wave_incl_scan(v, lane);
    __shared__ int wsum[4];
    if (lane == 63) wsum[w] = s;
    __syncthreads();
    int off = bsum[blockIdx.x];
    for (int k = 0; k < w; ++k) off += wsum[k];
    if (i < NN) offs[i] = off + s - v;   // exclusive
}

__global__ __launch_bounds__(256) void k_fill(const int* __restrict__ ei,
                                              int* __restrict__ deg,
                                              const int* __restrict__ offs,
                                              int* __restrict__ bucket) {
    int e = blockIdx.x * 256 + threadIdx.x;
    if (e >= EE) return;
    int r = ei[e];
    int c = ei[EE + e];
    int p = atomicSub(&deg[c], 1) - 1;   // deg reused as cursor; order irrelevant
    bucket[offs[c] + p] = r;
}

// ---------------- gather: h0[n] = x[n] + sum_{src->n} x[src] -------------------
__global__ __launch_bounds__(256) void k_gather(const float* __restrict__ x,
                                                const int* __restrict__ offs,
                                                const int* __restrict__ bucket,
                                                float* __restrict__ h0) {
    int gid = blockIdx.x * 256 + threadIdx.x;
    int n = gid >> 6;
    if (n >= NN) return;
    int lane = gid & 63;
    const float2* xr = reinterpret_cast<const float2*>(x);
    float2 acc = xr[(size_t)n * 64 + lane];
    int j = offs[n], jend = offs[n + 1];
    for (; j + 1 < jend; j += 2) {
        int a = bucket[j], b = bucket[j + 1];
        float2 va = xr[(size_t)a * 64 + lane];
        float2 vb = xr[(size_t)b * 64 + lane];
        acc.x += va.x + vb.x;
        acc.y += va.y + vb.y;
    }
    if (j < jend) {
        int a = bucket[j];
        float2 va = xr[(size_t)a * 64 + lane];
        acc.x += va.x;
        acc.y += va.y;
    }
    reinterpret_cast<float2*>(h0)[(size_t)n * 64 + lane] = acc;
}

// ---------------- prep: Wt[n][k] = bf16(W[k][n]) for both layers ----------------
__global__ __launch_bounds__(256) void k_prep(const float* __restrict__ W1,
                                              const float* __restrict__ W2,
                                              unsigned short* __restrict__ w1t,
                                              unsigned short* __restrict__ w2t) {
    int idx = blockIdx.x * 256 + threadIdx.x;
    if (idx >= 2 * DD * DD) return;
    const float* W = (idx < DD * DD) ? W1 : W2;
    unsigned short* O = (idx < DD * DD) ? w1t : w2t;
    int i = idx & (DD * DD - 1);
    int n = i >> 7, k = i & (DD - 1);
    O[i] = f2bf(W[k * DD + n]);      // O[n*128 + k] = W[k][n]
}

// ---------------- fused MLP: out = relu(h0@W1+b1)@W2 + b2 ----------------------
__global__ __launch_bounds__(256, 2) void k_mlp(const float* __restrict__ h0,
                                                const unsigned short* __restrict__ w1t,
                                                const unsigned short* __restrict__ w2t,
                                                const float* __restrict__ b1,
                                                const float* __restrict__ b2,
                                                float* __restrict__ out) {
    __shared__ unsigned short lds[DD * DD];  // 32 KB
    const int t  = threadIdx.x;
    const int w  = t >> 6, l = t & 63;
    const int wr = w >> 1, wc = w & 1;
    const int hi = l >> 4, lo = l & 15;
    const long base_row = (long)blockIdx.x * 128;

    bf16x8 bw1[4][4];
#pragma unroll
    for (int n = 0; n < 4; ++n)
#pragma unroll
        for (int k = 0; k < 4; ++k)
            bw1[n][k] = *reinterpret_cast<const bf16x8*>(
                w1t + (wc * 64 + n * 16 + lo) * DD + k * 32 + hi * 8);

#pragma unroll
    for (int it = 0; it < 16; ++it) {
        int idx = it * 1024 + t * 4;
        int row = idx >> 7, col = idx & (DD - 1);
        long g = base_row + row;
        float4 v = make_float4(0.f, 0.f, 0.f, 0.f);
        if (g < NN) v = *reinterpret_cast<const float4*>(h0 + g * DD + col);
        unsigned int u0 = (unsigned)f2bf(v.x) | ((unsigned)f2bf(v.y) << 16);
        unsigned int u1 = (unsigned)f2bf(v.z) | ((unsigned)f2bf(v.w) << 16);
        int byte = (row * 256 + col * 2) ^ ((row & 7) << 4);
        *reinterpret_cast<uint2*>(reinterpret_cast<char*>(lds) + byte) = make_uint2(u0, u1);
    }
    __syncthreads();

    const f32x4 zero = {0.f, 0.f, 0.f, 0.f};

    f32x4 acc[4][4];
#pragma unroll
    for (int m = 0; m < 4; ++m)
#pragma unroll
        for (int n = 0; n < 4; ++n) acc[m][n] = zero;
#pragma unroll
    for (int m = 0; m < 4; ++m) {
        bf16x8 a[4];
        int r = wr * 64 + m * 16 + lo;
#pragma unroll
        for (int k = 0; k < 4; ++k) {
            int byte = (r * 256 + k * 64 + hi * 16) ^ ((r & 7) << 4);
            a[k] = *reinterpret_cast<const bf16x8*>(reinterpret_cast<const char*>(lds) + byte);
        }
#pragma unroll
        for (int n = 0; n < 4; ++n)
#pragma unroll
            for (int k = 0; k < 4; ++k)
                acc[m][n] = __builtin_amdgcn_mfma_f32_16x16x32_bf16(a[k], bw1[n][k], acc[m][n], 0, 0, 0);
    }
    __syncthreads();

    float bias1[4];
#pragma unroll
    for (int n = 0; n < 4; ++n) bias1[n] = b1[wc * 64 + n * 16 + lo];
#pragma unroll
    for (int m = 0; m < 4; ++m)
#pragma unroll
        for (int n = 0; n < 4; ++n)
#pragma unroll
            for (int g = 0; g < 4; ++g) {
                int row = wr * 64 + m * 16 + hi * 4 + g;
                int col = wc * 64 + n * 16 + lo;
                float v = fmaxf(acc[m][n][g] + bias1[n], 0.f);
                int byte = (row * 256 + col * 2) ^ ((row & 7) << 4);
                *reinterpret_cast<unsigned short*>(reinterpret_cast<char*>(lds) + byte) = f2bf(v);
            }
    __syncthreads();

    bf16x8 bw2[4][4];
#pragma unroll
    for (int n = 0; n < 4; ++n)
#pragma unroll
        for (int k = 0; k < 4; ++k)
            bw2[n][k] = *reinterpret_cast<const bf16x8*>(
                w2t + (wc * 64 + n * 16 + lo) * DD + k * 32 + hi * 8);

    f32x4 acc2[4][4];
#pragma unroll
    for (int m = 0; m < 4; ++m)
#pragma unroll
        for (int n = 0; n < 4; ++n) acc2[m][n] = zero;
#pragma unroll
    for (int m = 0; m < 4; ++m) {
        bf16x8 a[4];
        int r = wr * 64 + m * 16 + lo;
#pragma unroll
        for (int k = 0; k < 4; ++k) {
            int byte = (r * 256 + k * 64 + hi * 16) ^ ((r & 7) << 4);
            a[k] = *reinterpret_cast<const bf16x8*>(reinterpret_cast<const char*>(lds) + byte);
        }
#pragma unroll
        for (int n = 0; n < 4; ++n)
#pragma unroll
            for (int k = 0; k < 4; ++k)
                acc2[m][n] = __builtin_amdgcn_mfma_f32_16x16x32_bf16(a[k], bw2[n][k], acc2[m][n], 0, 0, 0);
    }

    float bias2[4];
#pragma unroll
    for (int n = 0; n < 4; ++n) bias2[n] = b2[wc * 64 + n * 16 + lo];
#pragma unroll
    for (int m = 0; m < 4; ++m)
#pragma unroll
        for (int n = 0; n < 4; ++n)
#pragma unroll
            for (int g = 0; g < 4; ++g) {
                long row = base_row + wr * 64 + m * 16 + hi * 4 + g;
                if (row < NN)
                    out[row * DD + wc * 64 + n * 16 + lo] = acc2[m][n][g] + bias2[n];
            }
}

extern "C" void kernel_launch(void* const* d_in, const int* in_sizes, int n_in,
                              void* d_out, int out_size, void* d_ws, size_t ws_size,
                              hipStream_t stream) {
    const float* x  = (const float*)d_in[0];
    const int*   ei = (const int*)d_in[1];
    const float* W1 = (const float*)d_in[2];
    const float* b1 = (const float*)d_in[3];
    const float* W2 = (const float*)d_in[4];
    const float* b2 = (const float*)d_in[5];
    float* out = (float*)d_out;

    char* ws = (char*)d_ws;
    float* h0 = (float*)ws;                                   // 51,200,000 B
    unsigned short* w1t = (unsigned short*)(ws + 51200000);   // 32 KB
    unsigned short* w2t = w1t + DD * DD;                      // 32 KB
    int* deg    = (int*)(ws + 51200000 + 65536);              // NN ints
    int* offs   = deg + NN;                                   // NN+1 ints
    int* bsum   = offs + NN + 1;                              // NB ints (pad 512)
    int* bucket = bsum + 512;                                 // EE ints

    hipMemsetAsync(deg, 0, NN * sizeof(int), stream);
    k_prep<<<(2 * DD * DD + 255) / 256, 256, 0, stream>>>(W1, W2, w1t, w2t);
    k_hist<<<(EE + 255) / 256, 256, 0, stream>>>(ei, deg);
    k_scan1<<<NB, 256, 0, stream>>>(deg, bsum);
    k_scan2<<<1, 512, 0, stream>>>(bsum, offs);
    k_scan3<<<NB, 256, 0, stream>>>(deg, bsum, offs);
    k_fill<<<(EE + 255) / 256, 256, 0, stream>>>(ei, deg, offs, bucket);
    k_gather<<<(NN * 64 + 255) / 256, 256, 0, stream>>>(x, offs, bucket, h0);
    k_mlp<<<(NN + 127) / 128, 256, 0, stream>>>(h0, w1t, w2t, b1, b2, out);
}